// Round 3
// baseline (1223.308 us; speedup 1.0000x reference)
//
#include <hip/hip_runtime.h>

#define B_   2
#define S_   4096
#define H_   16
#define DK_  128
#define DV_  128
#define CK_  64
#define NC_  (S_/CK_)            // 64 chunks per sequence
#define QSCALE 0.08838834764831845f   // 128^-0.5

#define DOT4(a,b) ((a).x*(b).x + (a).y*(b).y + (a).z*(b).z + (a).w*(b).w)

static __device__ __forceinline__ unsigned short f2bf(float x) {
    unsigned u = __float_as_uint(x);
    unsigned r = u + 0x7fffu + ((u >> 16) & 1u);
    return (unsigned short)(r >> 16);
}
static __device__ __forceinline__ float bf2f(unsigned short h) {
    return __uint_as_float(((unsigned)h) << 16);
}
static __device__ __forceinline__ ushort4 pack4(float4 v) {
    ushort4 o; o.x = f2bf(v.x); o.y = f2bf(v.y); o.z = f2bf(v.z); o.w = f2bf(v.w);
    return o;
}
struct F8 { float4 lo, hi; };
static __device__ __forceinline__ F8 unpack8(uint4 p) {
    F8 r;
    r.lo.x = __uint_as_float(p.x << 16);  r.lo.y = __uint_as_float(p.x & 0xffff0000u);
    r.lo.z = __uint_as_float(p.y << 16);  r.lo.w = __uint_as_float(p.y & 0xffff0000u);
    r.hi.x = __uint_as_float(p.z << 16);  r.hi.y = __uint_as_float(p.z & 0xffff0000u);
    r.hi.z = __uint_as_float(p.w << 16);  r.hi.w = __uint_as_float(p.w & 0xffff0000u);
    return r;
}
static __device__ __forceinline__ float4 unpack4(uint2 p) {
    float4 r;
    r.x = __uint_as_float(p.x << 16);  r.y = __uint_as_float(p.x & 0xffff0000u);
    r.z = __uint_as_float(p.y << 16);  r.w = __uint_as_float(p.y & 0xffff0000u);
    return r;
}

// ---------------- Phase 1: per-chunk (2048 blocks, 2 blocks/CU) ----------------
__global__ __launch_bounds__(256, 2) void dr_phase1(
    const float* __restrict__ Q, const float* __restrict__ K,
    const float* __restrict__ V, const float* __restrict__ G,
    const float* __restrict__ Bt,
    unsigned short* __restrict__ Uw, unsigned short* __restrict__ KCDw,
    unsigned short* __restrict__ ATTNw,
    float* __restrict__ RQw, float* __restrict__ RKw, float* __restrict__ EGw)
{
    __shared__ float kn[64][132];              // 33792 B  normalized k (f32)
    __shared__ unsigned short bufh[64][136];   // 17408 B  v*beta, later q (bf16)
    __shared__ float T[64][68];                // 17408 B
    __shared__ float pt[2][64][2];             // 1024 B
    __shared__ float gcs[64], bet[64], w_s[64], rn[64], epos[64], eneg[64];

    const int tid = threadIdx.x;
    const int cid = blockIdx.x;
    const int n   = cid & (NC_ - 1);
    const int bh  = cid >> 6;
    const int h   = bh & (H_ - 1);
    const int b   = bh >> 4;
    const int rowbase = (b*S_ + n*CK_)*H_ + h;

    // load K (f32) + wave-scan cumsum(g)
    #pragma unroll
    for (int i = 0; i < 8; ++i) {
        int idx4 = tid + 256*i;
        int r = idx4 >> 5, c0 = (idx4 & 31) << 2;
        *(float4*)&kn[r][c0] = *(const float4*)(K + (size_t)(rowbase + r*H_)*DK_ + c0);
    }
    if (tid < 64) {
        float v = G[rowbase + tid*H_];
        bet[tid] = Bt[rowbase + tid*H_];
        #pragma unroll
        for (int d = 1; d < 64; d <<= 1) {
            float o = __shfl_up(v, d, 64);
            if (tid >= d) v += o;
        }
        gcs[tid] = v;
        float ep = expf(v);
        epos[tid] = ep; eneg[tid] = expf(-v);
        w_s[tid] = bet[tid]*ep;
    }
    __syncthreads();

    if (tid >= 64 && tid < 128) {
        int r = tid & 63;
        float s = 0.f;
        for (int c = 0; c < 128; c += 4) { float4 x = *(float4*)&kn[r][c]; s += DOT4(x,x); }
        rn[r] = rsqrtf(s + 1e-6f);
    }
    __syncthreads();

    if (tid < 64) RKw[cid*64 + tid] = rn[tid]*epos[63]*eneg[tid];
    if (tid == 128) EGw[cid] = epos[63];

    // scale kn rows; load v*beta -> bufh (bf16)
    #pragma unroll
    for (int i = 0; i < 8; ++i) {
        int idx4 = tid + 256*i;
        int r = idx4 >> 5, c0 = (idx4 & 31) << 2;
        float rr = rn[r];
        float4 kv = *(float4*)&kn[r][c0];
        kv.x *= rr; kv.y *= rr; kv.z *= rr; kv.w *= rr;
        *(float4*)&kn[r][c0] = kv;
        float bb = bet[r];
        float4 vv = *(const float4*)(V + (size_t)(rowbase + r*H_)*DV_ + c0);
        vv.x *= bb; vv.y *= bb; vv.z *= bb; vv.w *= bb;
        *(ushort4*)&bufh[r][c0] = pack4(vv);
    }
    __syncthreads();

    // T = -strict_lower((k*beta) @ k^T * decay), strided-row 4x4 tiles
    {
        const int mi = tid >> 4, mj = tid & 15;
        float acc[4][4] = {};
        for (int c = 0; c < 128; c += 4) {
            float4 a[4], bb[4];
            #pragma unroll
            for (int x = 0; x < 4; ++x) a[x] = *(float4*)&kn[mi + 16*x][c];
            #pragma unroll
            for (int y = 0; y < 4; ++y) bb[y] = *(float4*)&kn[mj + 16*y][c];
            #pragma unroll
            for (int x = 0; x < 4; ++x)
                #pragma unroll
                for (int y = 0; y < 4; ++y) acc[x][y] += DOT4(a[x], bb[y]);
        }
        #pragma unroll
        for (int x = 0; x < 4; ++x)
            #pragma unroll
            for (int y = 0; y < 4; ++y) {
                int i = mi + 16*x, j = mj + 16*y;
                T[i][j] = (i > j) ? (-bet[i]*epos[i]*eneg[j]*acc[x][y]) : 0.f;
            }
    }
    __syncthreads();

    // in-place unit-lower inverse, 2 rows per step (64 barriers)
    for (int i = 1; i < 64; i += 2) {
        const int j = tid & 63, p = (tid >> 6) & 1, rs = tid >> 7;
        const int row = i + rs;
        float s = 0.f;
        if (row < 64 && j < i)
            for (int l = j+1+p; l < i; l += 2) s += T[row][l]*T[l][j];
        pt[rs][j][p] = s;
        __syncthreads();
        if (tid < i && tid < 64) {
            float ti = T[i][tid] + pt[0][tid][0] + pt[0][tid][1];
            T[i][tid] = ti;
            if (i+1 < 64) {
                float ti1 = T[i+1][tid] + pt[1][tid][0] + pt[1][tid][1] + T[i+1][i]*ti;
                T[i+1][tid] = ti1;
            }
        }
        __syncthreads();
    }

    // U = (I+T) @ (v*beta)  -> bf16      (T f32 x bufh bf16)
    {
        unsigned short* Up = Uw + (size_t)cid*(CK_*DV_);
        for (int tt = tid; tt < 512; tt += 256) {
            const int i0 = (tt >> 5) << 2, c0 = (tt & 31) << 2;
            float4 acc[4];
            #pragma unroll
            for (int x = 0; x < 4; ++x) acc[x] = unpack4(*(uint2*)&bufh[i0+x][c0]);
            for (int j0 = 0; j0 <= i0; j0 += 4) {
                float4 t0 = *(float4*)&T[i0][j0],   t1 = *(float4*)&T[i0+1][j0];
                float4 t2 = *(float4*)&T[i0+2][j0], t3 = *(float4*)&T[i0+3][j0];
                float4 b0 = unpack4(*(uint2*)&bufh[j0][c0]);
                float4 b1 = unpack4(*(uint2*)&bufh[j0+1][c0]);
                float4 b2 = unpack4(*(uint2*)&bufh[j0+2][c0]);
                float4 b3 = unpack4(*(uint2*)&bufh[j0+3][c0]);
                acc[0].x += t0.x*b0.x + t0.y*b1.x + t0.z*b2.x + t0.w*b3.x;
                acc[0].y += t0.x*b0.y + t0.y*b1.y + t0.z*b2.y + t0.w*b3.y;
                acc[0].z += t0.x*b0.z + t0.y*b1.z + t0.z*b2.z + t0.w*b3.z;
                acc[0].w += t0.x*b0.w + t0.y*b1.w + t0.z*b2.w + t0.w*b3.w;
                acc[1].x += t1.x*b0.x + t1.y*b1.x + t1.z*b2.x + t1.w*b3.x;
                acc[1].y += t1.x*b0.y + t1.y*b1.y + t1.z*b2.y + t1.w*b3.y;
                acc[1].z += t1.x*b0.z + t1.y*b1.z + t1.z*b2.z + t1.w*b3.z;
                acc[1].w += t1.x*b0.w + t1.y*b1.w + t1.z*b2.w + t1.w*b3.w;
                acc[2].x += t2.x*b0.x + t2.y*b1.x + t2.z*b2.x + t2.w*b3.x;
                acc[2].y += t2.x*b0.y + t2.y*b1.y + t2.z*b2.y + t2.w*b3.y;
                acc[2].z += t2.x*b0.z + t2.y*b1.z + t2.z*b2.z + t2.w*b3.z;
                acc[2].w += t2.x*b0.w + t2.y*b1.w + t2.z*b2.w + t2.w*b3.w;
                acc[3].x += t3.x*b0.x + t3.y*b1.x + t3.z*b2.x + t3.w*b3.x;
                acc[3].y += t3.x*b0.y + t3.y*b1.y + t3.z*b2.y + t3.w*b3.y;
                acc[3].z += t3.x*b0.z + t3.y*b1.z + t3.z*b2.z + t3.w*b3.z;
                acc[3].w += t3.x*b0.w + t3.y*b1.w + t3.z*b2.w + t3.w*b3.w;
            }
            #pragma unroll
            for (int x = 0; x < 4; ++x)
                *(ushort4*)(Up + (i0+x)*DV_ + c0) = pack4(acc[x]);
        }
    }

    // KCD = (I+T) @ (k*beta*exp(gcs)) -> bf16    (T f32 x kn f32)
    {
        unsigned short* Kp = KCDw + (size_t)cid*(CK_*DK_);
        for (int tt = tid; tt < 512; tt += 256) {
            const int i0 = (tt >> 5) << 2, c0 = (tt & 31) << 2;
            float4 acc[4];
            #pragma unroll
            for (int x = 0; x < 4; ++x) {
                float wi = w_s[i0+x];
                float4 kv = *(float4*)&kn[i0+x][c0];
                acc[x].x = kv.x*wi; acc[x].y = kv.y*wi; acc[x].z = kv.z*wi; acc[x].w = kv.w*wi;
            }
            for (int j0 = 0; j0 <= i0; j0 += 4) {
                float w0 = w_s[j0], w1 = w_s[j0+1], w2 = w_s[j0+2], w3 = w_s[j0+3];
                float4 t0 = *(float4*)&T[i0][j0],   t1 = *(float4*)&T[i0+1][j0];
                float4 t2 = *(float4*)&T[i0+2][j0], t3 = *(float4*)&T[i0+3][j0];
                float4 b0 = *(float4*)&kn[j0][c0],   b1 = *(float4*)&kn[j0+1][c0];
                float4 b2 = *(float4*)&kn[j0+2][c0], b3 = *(float4*)&kn[j0+3][c0];
                b0.x*=w0; b0.y*=w0; b0.z*=w0; b0.w*=w0;
                b1.x*=w1; b1.y*=w1; b1.z*=w1; b1.w*=w1;
                b2.x*=w2; b2.y*=w2; b2.z*=w2; b2.w*=w2;
                b3.x*=w3; b3.y*=w3; b3.z*=w3; b3.w*=w3;
                acc[0].x += t0.x*b0.x + t0.y*b1.x + t0.z*b2.x + t0.w*b3.x;
                acc[0].y += t0.x*b0.y + t0.y*b1.y + t0.z*b2.y + t0.w*b3.y;
                acc[0].z += t0.x*b0.z + t0.y*b1.z + t0.z*b2.z + t0.w*b3.z;
                acc[0].w += t0.x*b0.w + t0.y*b1.w + t0.z*b2.w + t0.w*b3.w;
                acc[1].x += t1.x*b0.x + t1.y*b1.x + t1.z*b2.x + t1.w*b3.x;
                acc[1].y += t1.x*b0.y + t1.y*b1.y + t1.z*b2.y + t1.w*b3.y;
                acc[1].z += t1.x*b0.z + t1.y*b1.z + t1.z*b2.z + t1.w*b3.z;
                acc[1].w += t1.x*b0.w + t1.y*b1.w + t1.z*b2.w + t1.w*b3.w;
                acc[2].x += t2.x*b0.x + t2.y*b1.x + t2.z*b2.x + t2.w*b3.x;
                acc[2].y += t2.x*b0.y + t2.y*b1.y + t2.z*b2.y + t2.w*b3.y;
                acc[2].z += t2.x*b0.z + t2.y*b1.z + t2.z*b2.z + t2.w*b3.z;
                acc[2].w += t2.x*b0.w + t2.y*b1.w + t2.z*b2.w + t2.w*b3.w;
                acc[3].x += t3.x*b0.x + t3.y*b1.x + t3.z*b2.x + t3.w*b3.x;
                acc[3].y += t3.x*b0.y + t3.y*b1.y + t3.z*b2.y + t3.w*b3.y;
                acc[3].z += t3.x*b0.z + t3.y*b1.z + t3.z*b2.z + t3.w*b3.z;
                acc[3].w += t3.x*b0.w + t3.y*b1.w + t3.z*b2.w + t3.w*b3.w;
            }
            #pragma unroll
            for (int x = 0; x < 4; ++x)
                *(ushort4*)(Kp + (i0+x)*DK_ + c0) = pack4(acc[x]);
        }
    }
    __syncthreads();

    // q -> bufh (bf16, unscaled), row norms, RQ'
    #pragma unroll
    for (int i = 0; i < 8; ++i) {
        int idx4 = tid + 256*i;
        int r = idx4 >> 5, c0 = (idx4 & 31) << 2;
        float4 qv = *(const float4*)(Q + (size_t)(rowbase + r*H_)*DK_ + c0);
        *(ushort4*)&bufh[r][c0] = pack4(qv);
    }
    __syncthreads();
    if (tid < 64) {
        float s = 0.f;
        for (int c = 0; c < 128; c += 8) {
            F8 v = unpack8(*(uint4*)&bufh[tid][c]);
            s += DOT4(v.lo, v.lo) + DOT4(v.hi, v.hi);
        }
        rn[tid] = rsqrtf(s + 1e-6f)*QSCALE;
        RQw[cid*64 + tid] = rn[tid]*epos[tid];
    }
    __syncthreads();

    // attn = tril(q@k^T * decay) -> bf16 (q-scale folded into epilogue), strided tiles
    {
        unsigned short* Ap = ATTNw + (size_t)cid*(CK_*CK_);
        const int mi = tid >> 4, mj = tid & 15;
        float acc[4][4] = {};
        for (int c = 0; c < 128; c += 4) {
            float4 a[4], bb[4];
            #pragma unroll
            for (int x = 0; x < 4; ++x) a[x] = unpack4(*(uint2*)&bufh[mi + 16*x][c]);
            #pragma unroll
            for (int y = 0; y < 4; ++y) bb[y] = *(float4*)&kn[mj + 16*y][c];
            #pragma unroll
            for (int x = 0; x < 4; ++x)
                #pragma unroll
                for (int y = 0; y < 4; ++y) acc[x][y] += DOT4(a[x], bb[y]);
        }
        #pragma unroll
        for (int x = 0; x < 4; ++x) {
            int i = mi + 16*x;
            float fi = rn[i]*epos[i];
            #pragma unroll
            for (int y = 0; y < 4; ++y) {
                int j = mj + 16*y;
                float v = (j <= i) ? acc[x][y]*fi*eneg[j] : 0.f;
                Ap[i*CK_ + j] = f2bf(v);
            }
        }
    }
}

// ---------------- Phase 2: state recurrence (512 blocks = bh x 16 v-slices of 8) ----------------
__global__ __launch_bounds__(256, 2) void dr_phase2(
    const float* __restrict__ K,
    const unsigned short* __restrict__ Uw, const unsigned short* __restrict__ KCDw,
    const float* __restrict__ RKw, const float* __restrict__ EGw,
    unsigned short* __restrict__ STw)
{
    __shared__ unsigned short kch[64][136];  // 17408 B  kcd (bf16)
    __shared__ float kd[64][132];            // 33792 B  k*RK'
    __shared__ float stT[8][132];            // 4224 B   state^T slice [v][k]
    __shared__ float vn[64][12];             // 3072 B

    const int tid = threadIdx.x;
    const int vs = blockIdx.x & 15, bh = blockIdx.x >> 4;
    const int h = bh & (H_-1), b = bh >> 4;
    const int v0 = vs*8;

    for (int i = tid; i < 8*132; i += 256) (&stT[0][0])[i] = 0.f;
    __syncthreads();

    const int rv = tid >> 2, wv = (tid & 3)*2;       // vn tile: row rv, v-cols wv..wv+1
    const int ws = tid >> 5, k0s = (tid & 31)*4;     // state tile: v-row ws, k-cols k0s..+3

    for (int n = 0; n < NC_; ++n) {
        const int cid = bh*NC_ + n;
        const int rowbase = (b*S_ + n*CK_)*H_ + h;

        // store pre-update state for phase 3 (bf16)
        {
            float4 s = *(float4*)&stT[ws][k0s];
            *(ushort4*)(STw + ((size_t)cid*128 + v0 + ws)*128 + k0s) = pack4(s);
        }
        const float a_dec = EGw[cid];
        // loads: kcd packed copy, kd = K*RK'
        {
            const uint4* kcp = (const uint4*)(KCDw + (size_t)cid*8192);
            #pragma unroll
            for (int i = 0; i < 4; ++i) {
                int idx = tid + 256*i;
                int r = idx >> 4, c0 = (idx & 15)*8;
                *(uint4*)&kch[r][c0] = kcp[idx];
            }
            #pragma unroll
            for (int i = 0; i < 8; ++i) {
                int idx4 = tid + 256*i;
                int r = idx4 >> 5, c0 = (idx4 & 31)*4;
                float rk = RKw[cid*64 + r];
                float4 kv = *(const float4*)(K + (size_t)(rowbase + r*H_)*DK_ + c0);
                kv.x *= rk; kv.y *= rk; kv.z *= rk; kv.w *= rk;
                *(float4*)&kd[r][c0] = kv;
            }
        }
        float u0, u1;
        {
            unsigned uv = *(const unsigned*)(Uw + (size_t)cid*8192 + rv*128 + v0 + wv);
            u0 = bf2f((unsigned short)(uv & 0xffff));
            u1 = bf2f((unsigned short)(uv >> 16));
        }
        __syncthreads();

        // vn = u - kcd @ state
        {
            float s0 = u0, s1 = u1;
            for (int k0 = 0; k0 < 128; k0 += 8) {
                F8 a = unpack8(*(uint4*)&kch[rv][k0]);
                float4 b0a = *(float4*)&stT[wv][k0],   b0b = *(float4*)&stT[wv][k0+4];
                float4 b1a = *(float4*)&stT[wv+1][k0], b1b = *(float4*)&stT[wv+1][k0+4];
                s0 -= DOT4(a.lo, b0a) + DOT4(a.hi, b0b);
                s1 -= DOT4(a.lo, b1a) + DOT4(a.hi, b1b);
            }
            vn[rv][wv] = s0; vn[rv][wv+1] = s1;
        }
        __syncthreads();

        // stT = a*stT + vn^T @ kd
        {
            float4 acc = *(float4*)&stT[ws][k0s];
            acc.x *= a_dec; acc.y *= a_dec; acc.z *= a_dec; acc.w *= a_dec;
            for (int r = 0; r < 64; ++r) {
                float vv = vn[r][ws];
                float4 kv = *(float4*)&kd[r][k0s];
                acc.x += vv*kv.x; acc.y += vv*kv.y; acc.z += vv*kv.z; acc.w += vv*kv.w;
            }
            *(float4*)&stT[ws][k0s] = acc;
        }
        __syncthreads();
    }
}

// ---------------- Phase 3: outputs (4096 blocks = chunk x Dv-half, 2 blocks/CU) ----------------
__global__ __launch_bounds__(256, 2) void dr_phase3(
    const float* __restrict__ Q,
    const unsigned short* __restrict__ Uw, const unsigned short* __restrict__ KCDw,
    const unsigned short* __restrict__ ATTNw, const unsigned short* __restrict__ STw,
    const float* __restrict__ RQw, float* __restrict__ Out)
{
    __shared__ unsigned short qgh[64][136];  // 17408 B  q*rq (bf16)
    __shared__ unsigned short kch[64][136];  // 17408 B  kcd (bf16)
    __shared__ unsigned short STh[64][136];  // 17408 B  state^T rows (bf16)
    __shared__ unsigned short ath[64][72];   // 9216 B   attn (bf16)
    __shared__ float vnT[64][68];            // 17408 B  v_new^T (f32)

    const int tid = threadIdx.x;
    const int half = blockIdx.x & 1;
    const int cid = blockIdx.x >> 1;
    const int n = cid & (NC_-1), bh = cid >> 6;
    const int h = bh & (H_-1), b = bh >> 4;
    const int rowbase = (b*S_ + n*CK_)*H_ + h;
    const int vbase = half*64;

    #pragma unroll
    for (int i = 0; i < 8; ++i) {
        int idx4 = tid + 256*i;
        int r = idx4 >> 5, c0 = (idx4 & 31)*4;
        float rq = RQw[cid*64 + r];
        float4 qv = *(const float4*)(Q + (size_t)(rowbase + r*H_)*DK_ + c0);
        qv.x *= rq; qv.y *= rq; qv.z *= rq; qv.w *= rq;
        *(ushort4*)&qgh[r][c0] = pack4(qv);
    }
    {
        const uint4* kcp = (const uint4*)(KCDw + (size_t)cid*8192);
        const uint4* stp = (const uint4*)(STw + ((size_t)cid*128 + vbase)*128);
        #pragma unroll
        for (int i = 0; i < 4; ++i) {
            int idx = tid + 256*i;
            int r = idx >> 4, c0 = (idx & 15)*8;
            *(uint4*)&kch[r][c0] = kcp[idx];
            *(uint4*)&STh[r][c0] = stp[idx];
        }
        const uint4* atp = (const uint4*)(ATTNw + (size_t)cid*4096);
        #pragma unroll
        for (int i = 0; i < 2; ++i) {
            int idx = tid + 256*i;
            int r = idx >> 3, j0 = (idx & 7)*8;
            *(uint4*)&ath[r][j0] = atp[idx];
        }
    }
    __syncthreads();

    const int m = tid & 15;          // A-rows m, m+16, m+32, m+48
    const int n4 = (tid >> 4)*4;     // v-rows n4..n4+3

    // vn = u - kcd @ state   (output transposed into vnT[v][r])
    {
        float4 acc[4];
        #pragma unroll
        for (int x = 0; x < 4; ++x) {
            uint2 uv = *(const uint2*)(Uw + (size_t)cid*8192 + (m+16*x)*128 + vbase + n4);
            acc[x] = unpack4(uv);
        }
        for (int k0 = 0; k0 < 128; k0 += 8) {
            F8 a[4], bb[4];
            #pragma unroll
            for (int x = 0; x < 4; ++x) a[x] = unpack8(*(uint4*)&kch[m+16*x][k0]);
            #pragma unroll
            for (int y = 0; y < 4; ++y) bb[y] = unpack8(*(uint4*)&STh[n4+y][k0]);
            #pragma unroll
            for (int x = 0; x < 4; ++x) {
                acc[x].x -= DOT4(a[x].lo, bb[0].lo) + DOT4(a[x].hi, bb[0].hi);
                acc[x].y -= DOT4(a[x].lo, bb[1].lo) + DOT4(a[x].hi, bb[1].hi);
                acc[x].z -= DOT4(a[x].lo, bb[2].lo) + DOT4(a[x].hi, bb[2].hi);
                acc[x].w -= DOT4(a[x].lo, bb[3].lo) + DOT4(a[x].hi, bb[3].hi);
            }
        }
        #pragma unroll
        for (int x = 0; x < 4; ++x) {
            vnT[n4][m+16*x]   = acc[x].x;
            vnT[n4+1][m+16*x] = acc[x].y;
            vnT[n4+2][m+16*x] = acc[x].z;
            vnT[n4+3][m+16*x] = acc[x].w;
        }
    }
    __syncthreads();

    // o = qg @ state + attn @ vn
    {
        float4 acc[4] = {};
        for (int k0 = 0; k0 < 128; k0 += 8) {
            F8 a[4], bb[4];
            #pragma unroll
            for (int x = 0; x < 4; ++x) a[x] = unpack8(*(uint4*)&qgh[m+16*x][k0]);
            #pragma unroll
            for (int y = 0; y < 4; ++y) bb[y] = unpack8(*(uint4*)&STh[n4+y][k0]);
            #pragma unroll
            for (int x = 0; x < 4; ++x) {
                acc[x].x += DOT4(a[x].lo, bb[0].lo) + DOT4(a[x].hi, bb[0].hi);
                acc[x].y += DOT4(a[x].lo, bb[1].lo) + DOT4(a[x].hi, bb[1].hi);
                acc[x].z += DOT4(a[x].lo, bb[2].lo) + DOT4(a[x].hi, bb[2].hi);
                acc[x].w += DOT4(a[x].lo, bb[3].lo) + DOT4(a[x].hi, bb[3].hi);
            }
        }
        for (int j0 = 0; j0 < 64; j0 += 4) {
            float4 a[4], bb[4];
            #pragma unroll
            for (int x = 0; x < 4; ++x) a[x] = unpack4(*(uint2*)&ath[m+16*x][j0]);
            #pragma unroll
            for (int y = 0; y < 4; ++y) bb[y] = *(float4*)&vnT[n4+y][j0];
            #pragma unroll
            for (int x = 0; x < 4; ++x) {
                acc[x].x += DOT4(a[x], bb[0]);
                acc[x].y += DOT4(a[x], bb[1]);
                acc[x].z += DOT4(a[x], bb[2]);
                acc[x].w += DOT4(a[x], bb[3]);
            }
        }
        #pragma unroll
        for (int x = 0; x < 4; ++x)
            *(float4*)(Out + (size_t)(rowbase + (m+16*x)*H_)*DV_ + vbase + n4) = acc[x];
    }
}

extern "C" void kernel_launch(void* const* d_in, const int* in_sizes, int n_in,
                              void* d_out, int out_size, void* d_ws, size_t ws_size,
                              hipStream_t stream) {
    (void)in_sizes; (void)n_in; (void)out_size; (void)ws_size;
    const float* Q  = (const float*)d_in[0];
    const float* K  = (const float*)d_in[1];
    const float* V  = (const float*)d_in[2];
    const float* G  = (const float*)d_in[3];
    const float* Bt = (const float*)d_in[4];
    float* Out = (float*)d_out;

    // ws layout: U bf16 | KCD bf16 | ATTN bf16 | ST bf16 | RQ f32 | RK f32 | EG f32  = ~150 MB
    unsigned short* Uw    = (unsigned short*)d_ws;
    unsigned short* KCDw  = Uw    + (size_t)2048*64*128;
    unsigned short* ATTNw = KCDw  + (size_t)2048*64*128;
    unsigned short* STw   = ATTNw + (size_t)2048*64*64;
    float* RQw = (float*)(STw + (size_t)2048*128*128);
    float* RKw = RQw + 2048*64;
    float* EGw = RKw + 2048*64;

    dr_phase1<<<2048, 256, 0, stream>>>(Q, K, V, G, Bt, Uw, KCDw, ATTNw, RQw, RKw, EGw);
    dr_phase2<<<512, 256, 0, stream>>>(K, Uw, KCDw, RKw, EGw, STw);
    dr_phase3<<<4096, 256, 0, stream>>>(Q, Uw, KCDw, ATTNw, STw, RQw, Out);
}